// Round 8
// baseline (219.951 us; speedup 1.0000x reference)
//
#include <hip/hip_runtime.h>
#include <hip/hip_cooperative_groups.h>
#include <math.h>

namespace cg = cooperative_groups;

#define BB 2
#define HH 256
#define WW 832
#define HWIMG (HH * WW)
#define BHW (BB * HWIMG)

#define TXN 26            // tiles in x (832/32)
#define TYN 8             // tiles in y (256/32)
#define NTILES (BB * TXN * TYN)   // 416 == grid size
#define CAP 512           // per-tile candidate capacity
#define LDSK 128          // per-block keeper capacity (expect ~8 of 1024 px)

// ---------------------------------------------------------------------------
// Orientation at (i,j): 3x3 wrap box-blur (jnp.roll) -> jnp.gradient
// (one-sided at borders) -> atan2. Box sums of 0/1 exact in fp32; all 25
// loads independent -> one memory round trip. Bit-identical to dense pass.
// ---------------------------------------------------------------------------
__device__ inline float theta_at(const float* __restrict__ m, int i, int j) {
    int ri[5], cj[5];
#pragma unroll
    for (int t = 0; t < 5; ++t) {
        int r = i + t - 2; r = (r < 0) ? r + HH : (r >= HH ? r - HH : r);
        int c = j + t - 2; c = (c < 0) ? c + WW : (c >= WW ? c - WW : c);
        ri[t] = r * WW; cj[t] = c;
    }
    float S[5][5];
#pragma unroll
    for (int a = 0; a < 5; ++a)
#pragma unroll
        for (int c = 0; c < 5; ++c)
            S[a][c] = m[ri[a] + cj[c]];
    float ct[5], cm[5], cb[5];
#pragma unroll
    for (int c = 0; c < 5; ++c) {
        ct[c] = S[0][c] + S[1][c] + S[2][c];
        cm[c] = S[1][c] + S[2][c] + S[3][c];
        cb[c] = S[2][c] + S[3][c] + S[4][c];
    }
    float Bm = ct[1] + ct[2] + ct[3];
    float Bp = cb[1] + cb[2] + cb[3];
    float Bl = cm[0] + cm[1] + cm[2];
    float Br = cm[2] + cm[3] + cm[4];
    float Bc = cm[1] + cm[2] + cm[3];
    float gy = (i == 0) ? (Bp - Bc) : (i == HH - 1) ? (Bc - Bm) : 0.5f * (Bp - Bm);
    float gx = (j == 0) ? (Br - Bc) : (j == WW - 1) ? (Bc - Bl) : 0.5f * (Br - Bl);
    return atan2f(gy, gx);
}

// ---------------------------------------------------------------------------
// Single cooperative kernel: keeper detect -> grid.sync -> search+bin ->
// grid.sync -> per-tile diffuse. 416 blocks x 256 threads, block bid is
// also tile bid in phase 3.
// ---------------------------------------------------------------------------
__global__ void mega_kernel(const float4* __restrict__ src4, const float* __restrict__ src,
                            const float* __restrict__ dst,
                            const int* __restrict__ xx, const int* __restrict__ yy, int K,
                            int* __restrict__ counts, int* __restrict__ entries,
                            float* __restrict__ out) {
    __shared__ int kox[128], koy[128];
    __shared__ float kd[128];
    __shared__ int recs[LDSK];
    __shared__ float tss[LDSK];
    __shared__ int nkeep;
    __shared__ float wt[441];
    __shared__ float4 ent[CAP];

    cg::grid_group grid = cg::this_grid();
    int tid = threadIdx.x;
    int bid = blockIdx.x;

    if (tid == 0) { nkeep = 0; counts[bid] = 0; }
    for (int t = tid; t < K; t += 256) {
        int ox = xx[t], oy = yy[t];
        kox[t] = ox; koy[t] = oy;
        kd[t] = 20.0f * sqrtf((float)(ox * ox + oy * oy));
    }
    for (int t = tid; t < 441; t += 256) {
        int dy = t / 21 - 10;
        int dx = t % 21 - 10;
        wt[t] = expf(-sqrtf((float)(dx * dx + dy * dy)) / 5.0f);
    }
    __syncthreads();

    // ---- Phase 1: keeper detection, 4 px/thread (float4), LDS compaction ----
    {
        int t4 = bid * 256 + tid;            // BHW/4 threads total, exact
        float4 sv = src4[t4];
        int p0 = t4 * 4;
        int j0 = p0 % WW;                    // 4 | WW: row not straddled
        int r = p0 / WW;
        int i = r % HH;
        int b = r / HH;                      // 1024 | HWIMG: batch not straddled
        const float* sb = src + b * HWIMG;
        float svv[4] = {sv.x, sv.y, sv.z, sv.w};
#pragma unroll
        for (int q = 0; q < 4; ++q) {
            if (svv[q] > 0.5f) {
                int j = j0 + q;
                // smaller-linear-index nbrs: rows i-2,i-1 (dj -2..2), row i (dj -2,-1)
                float m = 0.f;
#pragma unroll
                for (int p = 0; p < 12; ++p) {
                    int di = (p < 5) ? -2 : (p < 10 ? -1 : 0);
                    int dj = (p < 5) ? (p - 2) : (p < 10 ? (p - 7) : (p - 12));
                    int ii = i + di, jj = j + dj;
                    bool inb = (ii >= 0) && (jj >= 0) && (jj < WW);
                    float v = sb[inb ? (ii * WW + jj) : 0];
                    m = fmaxf(m, inb ? v : 0.f);
                }
                if (m <= 0.5f) {
                    float ts = theta_at(sb, i, j);
                    int pos = atomicAdd(&nkeep, 1);      // LDS atomic
                    if (pos < LDSK) {
                        recs[pos] = j | (i << 10) | (b << 18);
                        tss[pos] = ts;
                    }
                }
            }
        }
    }
    grid.sync();   // counts[] zeroing visible to all before binning atomics

    // ---- Phase 2: wave-per-keeper search (lexicographic shuffle argmin) ----
    {
        int nk = (nkeep < LDSK) ? nkeep : LDSK;
        int lane = tid & 63;
        int wv = tid >> 6;                    // 0..3
        for (int w = wv; w < nk; w += 4) {
            int rec = recs[w];
            float ts = tss[w];
            int kj = rec & 1023;
            int ki = (rec >> 10) & 255;
            int kb = rec >> 18;
            const float* d = dst + kb * HWIMG;

            float best = 1e9f;
            int bk = 1 << 20;
#pragma unroll
            for (int rr = 0; rr < 2; ++rr) {
                int k = lane + rr * 64;
                if (k < K) {
                    int ii = ki + koy[k], jj = kj + kox[k];
                    if (ii >= 0 && ii < HH && jj >= 0 && jj < WW && d[ii * WW + jj] > 0.5f) {
                        float td = theta_at(d, ii, jj);   // ~2 active lanes/wave
                        float sc = kd[k] + 10.5f * (1.0f - cosf(ts - td));
                        if (sc < best || (sc == best && k < bk)) { best = sc; bk = k; }
                    }
                }
            }
#pragma unroll
            for (int off = 32; off >= 1; off >>= 1) {
                float ob = __shfl_down(best, off, 64);
                int ok = __shfl_down(bk, off, 64);
                if (ob < best || (ob == best && ok < bk)) { best = ob; bk = ok; }
            }
            if (lane == 0 && best < 5e8f) {
                int dx = kox[bk], dy = koy[bk];
                int packed = kj | (ki << 10) | ((dx + 7) << 18) | ((dy + 3) << 22);
                int tx0 = max(kj - 10, 0) >> 5, tx1 = min(kj + 10, WW - 1) >> 5;
                int ty0 = max(ki - 10, 0) >> 5, ty1 = min(ki + 10, HH - 1) >> 5;
                for (int ty = ty0; ty <= ty1; ++ty)
                    for (int tx = tx0; tx <= tx1; ++tx) {
                        int tile = (kb * TYN + ty) * TXN + tx;
                        int pos = atomicAdd(&counts[tile], 1);   // 416 addrs
                        if (pos < CAP) entries[tile * CAP + pos] = packed;
                    }
            }
        }
    }
    grid.sync();   // bins complete & visible

    // ---- Phase 3: per-tile diffusion; tile == bid ----
    {
        int b = bid / (TYN * TXN);
        int rem = bid % (TYN * TXN);
        int ty = rem / TXN;
        int tx = rem % TXN;
        int cnt = counts[bid];
        if (cnt > CAP) cnt = CAP;
        const int* e = entries + bid * CAP;
        for (int t = tid; t < cnt; t += 256) {
            int p = e[t];
            ent[t] = make_float4((float)(p & 1023), (float)((p >> 10) & 255),
                                 (float)(((p >> 18) & 15) - 7), (float)(((p >> 22) & 7) - 3));
        }
        __syncthreads();

        int j = tx * 32 + (tid & 31);
        int i0 = ty * 32 + (tid >> 5) * 4;
        float nx0 = 0, ny0 = 0, de0 = 0;
        float nx1 = 0, ny1 = 0, de1 = 0;
        float nx2 = 0, ny2 = 0, de2 = 0;
        float nx3 = 0, ny3 = 0, de3 = 0;

        for (int c = 0; c < cnt; ++c) {
            float4 E = ent[c];
            int dj = (int)E.x - j;
            if (dj < -10 || dj > 10) continue;
            int di = (int)E.y - i0;
            const float* wrow = &wt[dj + 10];
            if (di >= -10 && di <= 10) { float w = wrow[(di + 10) * 21]; de0 += w; nx0 += w * E.z; ny0 += w * E.w; }
            if (di >= -9  && di <= 11) { float w = wrow[(di + 9)  * 21]; de1 += w; nx1 += w * E.z; ny1 += w * E.w; }
            if (di >= -8  && di <= 12) { float w = wrow[(di + 8)  * 21]; de2 += w; nx2 += w * E.z; ny2 += w * E.w; }
            if (di >= -7  && di <= 13) { float w = wrow[(di + 7)  * 21]; de3 += w; nx3 += w * E.z; ny3 += w * E.w; }
        }

        int obase = b * 2 * HWIMG;
        float inv;
        inv = 0.6f / (de0 + 1e-6f);
        out[obase + (i0 + 0) * WW + j] = (float)j + nx0 * inv;
        out[obase + HWIMG + (i0 + 0) * WW + j] = (float)(i0 + 0) + ny0 * inv;
        inv = 0.6f / (de1 + 1e-6f);
        out[obase + (i0 + 1) * WW + j] = (float)j + nx1 * inv;
        out[obase + HWIMG + (i0 + 1) * WW + j] = (float)(i0 + 1) + ny1 * inv;
        inv = 0.6f / (de2 + 1e-6f);
        out[obase + (i0 + 2) * WW + j] = (float)j + nx2 * inv;
        out[obase + HWIMG + (i0 + 2) * WW + j] = (float)(i0 + 2) + ny2 * inv;
        inv = 0.6f / (de3 + 1e-6f);
        out[obase + (i0 + 3) * WW + j] = (float)j + nx3 * inv;
        out[obase + HWIMG + (i0 + 3) * WW + j] = (float)(i0 + 3) + ny3 * inv;
    }
}

// ---------------------------------------------------------------------------
extern "C" void kernel_launch(void* const* d_in, const int* in_sizes, int n_in,
                              void* d_out, int out_size, void* d_ws, size_t ws_size,
                              hipStream_t stream) {
    const float* src = (const float*)d_in[0];
    const float* dst = (const float*)d_in[1];
    const int* xx = (const int*)d_in[2];
    const int* yy = (const int*)d_in[3];
    int K = in_sizes[2];  // 105

    int* counts  = (int*)d_ws;                 // [NTILES]
    int* entries = counts + NTILES;            // [NTILES*CAP]
    float* out = (float*)d_out;
    const float4* src4 = (const float4*)src;

    void* args[] = {(void*)&src4, (void*)&src, (void*)&dst, (void*)&xx, (void*)&yy,
                    (void*)&K, (void*)&counts, (void*)&entries, (void*)&out};
    hipLaunchCooperativeKernel((void*)mega_kernel, dim3(NTILES), dim3(256),
                               args, 0, stream);
}

// Round 9
// 117.221 us; speedup vs baseline: 1.8764x; 1.8764x over previous
//
#include <hip/hip_runtime.h>
#include <math.h>

#define BB 2
#define HH 256
#define WW 832
#define HWIMG (HH * WW)

#define TXN 26            // tiles in x (832/32)
#define TYN 8             // tiles in y (256/32)
#define CAP 256           // per-tile keeper capacity (expect ~30)

// src halo: keeper range tile+-10, keep-test & theta +-2  -> 56x56
#define SH 56
#define SW 56
// dst halo: probe range keeper+-(7,3), theta +-2 -> 62 rows x 70 cols
#define DH 62
#define DW 70

// ---------------------------------------------------------------------------
// Orientation from an LDS-staged wrapped window. Identical arithmetic to the
// dense pass: 3x3 wrap box-blur (values staged pre-wrapped; local offsets
// reproduce jnp.roll because the staging index map is continuous), then
// jnp.gradient one-sided at *global* borders, then atan2.
// (ly,lx) = local center with >=2 margin on all sides; (gi,gj) = global.
// ---------------------------------------------------------------------------
__device__ inline float theta_lds(const float* a, int pitch, int ly, int lx,
                                  int gi, int gj) {
    float S[5][5];
#pragma unroll
    for (int r = 0; r < 5; ++r)
#pragma unroll
        for (int c = 0; c < 5; ++c)
            S[r][c] = a[(ly + r - 2) * pitch + (lx + c - 2)];
    float ct[5], cm[5], cb[5];
#pragma unroll
    for (int c = 0; c < 5; ++c) {
        ct[c] = S[0][c] + S[1][c] + S[2][c];
        cm[c] = S[1][c] + S[2][c] + S[3][c];
        cb[c] = S[2][c] + S[3][c] + S[4][c];
    }
    float Bm = ct[1] + ct[2] + ct[3];   // blur(gi-1,gj)
    float Bp = cb[1] + cb[2] + cb[3];   // blur(gi+1,gj)
    float Bl = cm[0] + cm[1] + cm[2];   // blur(gi,gj-1)
    float Br = cm[2] + cm[3] + cm[4];   // blur(gi,gj+1)
    float Bc = cm[1] + cm[2] + cm[3];   // blur(gi,gj)
    float gy = (gi == 0) ? (Bp - Bc) : (gi == HH - 1) ? (Bc - Bm) : 0.5f * (Bp - Bm);
    float gx = (gj == 0) ? (Br - Bc) : (gj == WW - 1) ? (Bc - Bl) : 0.5f * (Br - Bl);
    return atan2f(gy, gx);
}

// ---------------------------------------------------------------------------
// One block per 32x32 output tile; fully self-contained (no cross-block deps,
// no global atomics, no workspace). Phases (LDS-local, __syncthreads only):
//   0: stage wrapped src/dst halos + offset/weight tables
//   1: keeper detect over tile+-10 region (5x5 min-lin-index rule)
//   2: wave-per-keeper 105-offset search from LDS (lex (score,k) argmin)
//   3: 21x21 diffusion from the block's candidate list; write coords
// ---------------------------------------------------------------------------
__global__ void __launch_bounds__(256, 2)
bnmorph_kernel(const float* __restrict__ src, const float* __restrict__ dst,
               const int* __restrict__ xx, const int* __restrict__ yy, int K,
               float* __restrict__ out) {
    __shared__ float srcW[SH * SW];
    __shared__ float dstW[DH * DW];
    __shared__ float wt[441];
    __shared__ int kox[128], koy[128];
    __shared__ float kd[128];
    __shared__ float4 ent[CAP];        // (gj, gi, ts->dx, 0->dy); x=-1e4 if inactive
    __shared__ int nkeep;

    int tid = threadIdx.x;
    int tx = blockIdx.x, ty = blockIdx.y, b = blockIdx.z;
    int ti = ty * 32, tj = tx * 32;
    const float* sb = src + b * HWIMG;
    const float* db = dst + b * HWIMG;

    if (tid == 0) nkeep = 0;
    for (int t = tid; t < K; t += 256) {
        int ox = xx[t], oy = yy[t];
        kox[t] = ox; koy[t] = oy;
        kd[t] = 20.0f * sqrtf((float)(ox * ox + oy * oy));
    }
    for (int t = tid; t < 441; t += 256) {
        int dy = t / 21 - 10;
        int dx = t % 21 - 10;
        wt[t] = expf(-sqrtf((float)(dx * dx + dy * dy)) / 5.0f);
    }
    // stage wrapped halos (indices pre-wrapped; map continuous in ly/lx)
    const int SR0 = ti - 12, SC0 = tj - 12;
    for (int t = tid; t < SH * SW; t += 256) {
        int gi = SR0 + t / SW; gi = (gi + HH) % HH;
        int gj = SC0 + t % SW; gj = (gj + WW) % WW;
        srcW[t] = sb[gi * WW + gj];
    }
    const int DR0 = ti - 15, DC0 = tj - 19;
    for (int t = tid; t < DH * DW; t += 256) {
        int gi = DR0 + t / DW; gi = (gi + HH) % HH;
        int gj = DC0 + t % DW; gj = (gj + WW) % WW;
        dstW[t] = db[gi * WW + gj];
    }
    __syncthreads();

    // ---- Phase 1: keeper detection over the 52x52 influence region ----
    for (int t = tid; t < 52 * 52; t += 256) {
        int ry = t / 52, rx = t % 52;
        int gi = ti - 10 + ry;
        int gj = tj - 10 + rx;
        if (gi < 0 || gi >= HH || gj < 0 || gj >= WW) continue;
        int sly = ry + 2, slx = rx + 2;
        if (srcW[sly * SW + slx] > 0.5f) {
            // smaller-lin-index nbrs: rows -2,-1 (dj -2..2), row 0 (dj -2,-1)
            float m = 0.f;
#pragma unroll
            for (int p = 0; p < 12; ++p) {
                int di = (p < 5) ? -2 : (p < 10 ? -1 : 0);
                int dj = (p < 5) ? (p - 2) : (p < 10 ? (p - 7) : (p - 12));
                int ii = gi + di, jj = gj + dj;
                bool inb = (ii >= 0) && (jj >= 0) && (jj < WW);
                float v = srcW[(sly + di) * SW + slx + dj];   // always in-range
                m = fmaxf(m, inb ? v : 0.f);
            }
            if (m <= 0.5f) {
                float ts = theta_lds(srcW, SW, sly, slx, gi, gj);
                int pos = atomicAdd(&nkeep, 1);               // LDS atomic
                if (pos < CAP) ent[pos] = make_float4((float)gj, (float)gi, ts, 0.f);
            }
        }
    }
    __syncthreads();

    // ---- Phase 2: wave-per-keeper search, all from LDS ----
    int nk = (nkeep < CAP) ? nkeep : CAP;
    {
        int lane = tid & 63;
        int wv = tid >> 6;                 // 0..3
        for (int w = wv; w < nk; w += 4) {
            float4 E = ent[w];
            int gj = (int)E.x, gi = (int)E.y;
            float ts = E.z;

            float best = 1e9f;
            int bk = 1 << 20;
#pragma unroll
            for (int rr = 0; rr < 2; ++rr) {
                int k = lane + rr * 64;
                if (k < K) {
                    int pi = gi + koy[k], pj = gj + kox[k];
                    if (pi >= 0 && pi < HH && pj >= 0 && pj < WW) {
                        int dly = pi - DR0, dlx = pj - DC0;
                        if (dstW[dly * DW + dlx] > 0.5f) {
                            float td = theta_lds(dstW, DW, dly, dlx, pi, pj);
                            float sc = kd[k] + 10.5f * (1.0f - cosf(ts - td));
                            if (sc < best || (sc == best && k < bk)) { best = sc; bk = k; }
                        }
                    }
                }
            }
#pragma unroll
            for (int off = 32; off >= 1; off >>= 1) {
                float ob = __shfl_down(best, off, 64);
                int ok = __shfl_down(bk, off, 64);
                if (ob < best || (ob == best && ok < bk)) { best = ob; bk = ok; }
            }
            if (lane == 0) {
                if (best < 5e8f) {
                    ent[w].z = (float)kox[bk];
                    ent[w].w = (float)koy[bk];
                } else {
                    ent[w].x = -1e4f;      // inactive: auto-skipped by dj test
                }
            }
        }
    }
    __syncthreads();

    // ---- Phase 3: 21x21 diffusion from candidate list; write coords ----
    {
        int j = tj + (tid & 31);
        int i0 = ti + (tid >> 5) * 4;
        float nx0 = 0, ny0 = 0, de0 = 0;
        float nx1 = 0, ny1 = 0, de1 = 0;
        float nx2 = 0, ny2 = 0, de2 = 0;
        float nx3 = 0, ny3 = 0, de3 = 0;

        for (int c = 0; c < nk; ++c) {
            float4 E = ent[c];
            int dj = (int)E.x - j;
            if (dj < -10 || dj > 10) continue;
            int di = (int)E.y - i0;
            const float* wrow = &wt[dj + 10];
            if (di >= -10 && di <= 10) { float w = wrow[(di + 10) * 21]; de0 += w; nx0 += w * E.z; ny0 += w * E.w; }
            if (di >= -9  && di <= 11) { float w = wrow[(di + 9)  * 21]; de1 += w; nx1 += w * E.z; ny1 += w * E.w; }
            if (di >= -8  && di <= 12) { float w = wrow[(di + 8)  * 21]; de2 += w; nx2 += w * E.z; ny2 += w * E.w; }
            if (di >= -7  && di <= 13) { float w = wrow[(di + 7)  * 21]; de3 += w; nx3 += w * E.z; ny3 += w * E.w; }
        }

        int obase = b * 2 * HWIMG;
        float inv;
        inv = 0.6f / (de0 + 1e-6f);
        out[obase + (i0 + 0) * WW + j] = (float)j + nx0 * inv;
        out[obase + HWIMG + (i0 + 0) * WW + j] = (float)(i0 + 0) + ny0 * inv;
        inv = 0.6f / (de1 + 1e-6f);
        out[obase + (i0 + 1) * WW + j] = (float)j + nx1 * inv;
        out[obase + HWIMG + (i0 + 1) * WW + j] = (float)(i0 + 1) + ny1 * inv;
        inv = 0.6f / (de2 + 1e-6f);
        out[obase + (i0 + 2) * WW + j] = (float)j + nx2 * inv;
        out[obase + HWIMG + (i0 + 2) * WW + j] = (float)(i0 + 2) + ny2 * inv;
        inv = 0.6f / (de3 + 1e-6f);
        out[obase + (i0 + 3) * WW + j] = (float)j + nx3 * inv;
        out[obase + HWIMG + (i0 + 3) * WW + j] = (float)(i0 + 3) + ny3 * inv;
    }
}

// ---------------------------------------------------------------------------
extern "C" void kernel_launch(void* const* d_in, const int* in_sizes, int n_in,
                              void* d_out, int out_size, void* d_ws, size_t ws_size,
                              hipStream_t stream) {
    const float* src = (const float*)d_in[0];
    const float* dst = (const float*)d_in[1];
    const int* xx = (const int*)d_in[2];
    const int* yy = (const int*)d_in[3];
    int K = in_sizes[2];  // 105

    bnmorph_kernel<<<dim3(TXN, TYN, BB), dim3(256), 0, stream>>>(
        src, dst, xx, yy, K, (float*)d_out);
}

// Round 10
// 91.686 us; speedup vs baseline: 2.3990x; 1.2785x over previous
//
#include <hip/hip_runtime.h>
#include <math.h>

#define BB 2
#define HH 256
#define WW 832
#define HWIMG (HH * WW)

#define TX2 52            // 16-px tiles in x (832/16)
#define TY2 16            // 16-px tiles in y (256/16)
#define SEG 64            // per-tile keeper-result capacity (expect ~5)
#define ECAP 192          // diffuse candidate capacity (expect ~25)

// ---------------------------------------------------------------------------
// Orientation at (i,j): 3x3 wrap box-blur (jnp.roll) -> jnp.gradient
// (one-sided at borders) -> atan2. Box sums of 0/1 exact in fp32; all 25
// loads independent -> one memory round trip. Bit-identical to dense pass.
// ---------------------------------------------------------------------------
__device__ inline float theta_at(const float* __restrict__ m, int i, int j) {
    int ri[5], cj[5];
#pragma unroll
    for (int t = 0; t < 5; ++t) {
        int r = i + t - 2; r = (r < 0) ? r + HH : (r >= HH ? r - HH : r);
        int c = j + t - 2; c = (c < 0) ? c + WW : (c >= WW ? c - WW : c);
        ri[t] = r * WW; cj[t] = c;
    }
    float S[5][5];
#pragma unroll
    for (int a = 0; a < 5; ++a)
#pragma unroll
        for (int c = 0; c < 5; ++c)
            S[a][c] = m[ri[a] + cj[c]];
    float ct[5], cm[5], cb[5];
#pragma unroll
    for (int c = 0; c < 5; ++c) {
        ct[c] = S[0][c] + S[1][c] + S[2][c];
        cm[c] = S[1][c] + S[2][c] + S[3][c];
        cb[c] = S[2][c] + S[3][c] + S[4][c];
    }
    float Bm = ct[1] + ct[2] + ct[3];
    float Bp = cb[1] + cb[2] + cb[3];
    float Bl = cm[0] + cm[1] + cm[2];
    float Br = cm[2] + cm[3] + cm[4];
    float Bc = cm[1] + cm[2] + cm[3];
    float gy = (i == 0) ? (Bp - Bc) : (i == HH - 1) ? (Bc - Bm) : 0.5f * (Bp - Bm);
    float gx = (j == 0) ? (Br - Bc) : (j == WW - 1) ? (Bc - Bl) : 0.5f * (Br - Bl);
    return atan2f(gy, gx);
}

// ---------------------------------------------------------------------------
// Kernel A: one block per 16x16 tile. Keeper detect (own tile only) ->
// wave-per-keeper 105-offset search (global L1/L2 reads) -> owner-writes
// seg[tile]/cnt[tile]. No global atomics; no init required.
// packed: j(10b) | i<<10(8b) | b<<18(1b) | (dx+7)<<19(4b) | (dy+3)<<23(3b);
// -1 = keeper with no hit (inactive).
// ---------------------------------------------------------------------------
__global__ void prep_search_kernel(const float* __restrict__ src, const float* __restrict__ dst,
                                   const int* __restrict__ xx, const int* __restrict__ yy, int K,
                                   int* __restrict__ cnt, int* __restrict__ seg) {
    __shared__ int kox[128], koy[128];
    __shared__ float kd[128];
    __shared__ int recs[SEG];
    __shared__ float tss[SEG];
    __shared__ int outv[SEG];
    __shared__ int nkeep;

    int tid = threadIdx.x;
    if (tid == 0) nkeep = 0;
    for (int t = tid; t < K; t += 256) {
        int ox = xx[t], oy = yy[t];
        kox[t] = ox; koy[t] = oy;
        kd[t] = 20.0f * sqrtf((float)(ox * ox + oy * oy));
    }
    __syncthreads();

    int txi = blockIdx.x, tyi = blockIdx.y, b = blockIdx.z;
    int gi = tyi * 16 + (tid >> 4);
    int gj = txi * 16 + (tid & 15);
    const float* sb = src + b * HWIMG;
    const float* db = dst + b * HWIMG;

    // ---- Phase 1: keeper detection on own pixel ----
    if (sb[gi * WW + gj] > 0.5f) {
        // smaller-lin-index nbrs: rows -2,-1 (dj -2..2), row 0 (dj -2,-1)
        float m = 0.f;
#pragma unroll
        for (int p = 0; p < 12; ++p) {
            int di = (p < 5) ? -2 : (p < 10 ? -1 : 0);
            int dj = (p < 5) ? (p - 2) : (p < 10 ? (p - 7) : (p - 12));
            int ii = gi + di, jj = gj + dj;
            bool inb = (ii >= 0) && (jj >= 0) && (jj < WW);
            float v = sb[inb ? (ii * WW + jj) : 0];
            m = fmaxf(m, inb ? v : 0.f);
        }
        if (m <= 0.5f) {
            float ts = theta_at(sb, gi, gj);
            int pos = atomicAdd(&nkeep, 1);        // LDS atomic
            if (pos < SEG) { recs[pos] = gj | (gi << 10); tss[pos] = ts; }
        }
    }
    __syncthreads();

    // ---- Phase 2: wave-per-keeper search (lex (score,k) argmin) ----
    int nk = (nkeep < SEG) ? nkeep : SEG;
    int lane = tid & 63;
    int wv = tid >> 6;
    for (int w = wv; w < nk; w += 4) {
        int rec = recs[w];
        int kj = rec & 1023;
        int ki = rec >> 10;
        float ts = tss[w];

        float best = 1e9f;
        int bk = 1 << 20;
#pragma unroll
        for (int rr = 0; rr < 2; ++rr) {
            int k = lane + rr * 64;
            if (k < K) {
                int pi = ki + koy[k], pj = kj + kox[k];
                if (pi >= 0 && pi < HH && pj >= 0 && pj < WW && db[pi * WW + pj] > 0.5f) {
                    float td = theta_at(db, pi, pj);   // ~2 active lanes/wave
                    float sc = kd[k] + 10.5f * (1.0f - cosf(ts - td));
                    if (sc < best || (sc == best && k < bk)) { best = sc; bk = k; }
                }
            }
        }
#pragma unroll
        for (int off = 32; off >= 1; off >>= 1) {
            float ob = __shfl_down(best, off, 64);
            int ok = __shfl_down(bk, off, 64);
            if (ob < best || (ob == best && ok < bk)) { best = ob; bk = ok; }
        }
        if (lane == 0)
            outv[w] = (best < 5e8f)
                ? (rec | (b << 18) | ((kox[bk] + 7) << 19) | ((koy[bk] + 3) << 23))
                : -1;
    }
    __syncthreads();

    // ---- Owner-writes segment (no atomics, no init needed) ----
    int tile = (b * TY2 + tyi) * TX2 + txi;
    if (tid < nk) seg[tile * SEG + tid] = outv[tid];
    if (tid == 0) cnt[tile] = nk;
}

// ---------------------------------------------------------------------------
// Kernel B: one block per 16x16 tile. Gather 3x3 neighbor segments (+-10<16)
// into LDS, then 21x21 weighted diffusion, 1 px/thread.
// ---------------------------------------------------------------------------
__global__ void diffuse_kernel(const int* __restrict__ cnt, const int* __restrict__ seg,
                               float* __restrict__ out) {
    __shared__ float wt[441];
    __shared__ float4 ent[ECAP];
    __shared__ int ncnt[9];
    __shared__ int ne;

    int tid = threadIdx.x;
    if (tid == 0) ne = 0;
    for (int t = tid; t < 441; t += 256) {
        int dy = t / 21 - 10;
        int dx = t % 21 - 10;
        wt[t] = expf(-sqrtf((float)(dx * dx + dy * dy)) / 5.0f);
    }
    int txi = blockIdx.x, tyi = blockIdx.y, b = blockIdx.z;
    if (tid < 9) {
        int nty = tyi + tid / 3 - 1;
        int ntx = txi + tid % 3 - 1;
        ncnt[tid] = (nty >= 0 && nty < TY2 && ntx >= 0 && ntx < TX2)
                        ? cnt[(b * TY2 + nty) * TX2 + ntx] : 0;
    }
    __syncthreads();

    for (int t = tid; t < 9 * SEG; t += 256) {
        int q = t / SEG, slot = t % SEG;
        if (slot < ncnt[q]) {
            int nty = tyi + q / 3 - 1;
            int ntx = txi + q % 3 - 1;
            int v = seg[((b * TY2 + nty) * TX2 + ntx) * SEG + slot];
            if (v != -1) {
                int pos = atomicAdd(&ne, 1);       // LDS atomic
                if (pos < ECAP)
                    ent[pos] = make_float4((float)(v & 1023), (float)((v >> 10) & 255),
                                           (float)(((v >> 19) & 15) - 7),
                                           (float)(((v >> 23) & 7) - 3));
            }
        }
    }
    __syncthreads();

    int nn = (ne < ECAP) ? ne : ECAP;
    int gj = txi * 16 + (tid & 15);
    int gi = tyi * 16 + (tid >> 4);
    float nx = 0.f, ny = 0.f, de = 0.f;
    for (int c = 0; c < nn; ++c) {
        float4 E = ent[c];                          // broadcast LDS read
        int dj = (int)E.x - gj;
        int di = (int)E.y - gi;
        if (dj >= -10 && dj <= 10 && di >= -10 && di <= 10) {
            float w = wt[(di + 10) * 21 + dj + 10];
            de += w; nx += w * E.z; ny += w * E.w;
        }
    }
    float inv = 0.6f / (de + 1e-6f);
    int obase = b * 2 * HWIMG;
    out[obase + gi * WW + gj] = (float)gj + nx * inv;
    out[obase + HWIMG + gi * WW + gj] = (float)gi + ny * inv;
}

// ---------------------------------------------------------------------------
extern "C" void kernel_launch(void* const* d_in, const int* in_sizes, int n_in,
                              void* d_out, int out_size, void* d_ws, size_t ws_size,
                              hipStream_t stream) {
    const float* src = (const float*)d_in[0];
    const float* dst = (const float*)d_in[1];
    const int* xx = (const int*)d_in[2];
    const int* yy = (const int*)d_in[3];
    int K = in_sizes[2];  // 105

    int* cnt = (int*)d_ws;                          // [BB*TY2*TX2]
    int* seg = cnt + BB * TY2 * TX2;                // [BB*TY2*TX2*SEG]
    float* out = (float*)d_out;

    dim3 grid(TX2, TY2, BB);
    prep_search_kernel<<<grid, dim3(256), 0, stream>>>(src, dst, xx, yy, K, cnt, seg);
    diffuse_kernel<<<grid, dim3(256), 0, stream>>>(cnt, seg, out);
}